// Round 1
// baseline (1397.416 us; speedup 1.0000x reference)
//
#include <hip/hip_runtime.h>
#include <cstdint>
#include <cstddef>

#define N_NODES 50000
#define E_EDGES 800000
#define INCH 128
#define HID 64
#define HEADS 4
#define NHD 256      // HEADS*HID
#define NGRAPH 64
#define DCAT 640     // 128 + 256 + 256
#define NEG_SLOPE 0.2f

// ---------------- GEMM: C[M,Nc] = A[M,K] @ B[K,Nc], fp32, row-major ----------
#define BM 128
#define BN 128
#define BKK 8

__global__ __launch_bounds__(256, 2) void gemm_f32(
    const float* __restrict__ A, const float* __restrict__ B,
    float* __restrict__ C, int M, int K, int Nc)
{
    __shared__ float As[BKK][BM];
    __shared__ float Bs[BKK][BN];
    const int t  = threadIdx.x;
    const int tx = t & 15, ty = t >> 4;
    const int row0 = blockIdx.x * BM;
    const int col0 = blockIdx.y * BN;

    float acc[8][8];
#pragma unroll
    for (int i = 0; i < 8; ++i)
#pragma unroll
        for (int j = 0; j < 8; ++j) acc[i][j] = 0.f;

    const int ar = t >> 1;          // 0..127
    const int ac = (t & 1) * 4;     // 0 or 4
    const int br = t >> 5;          // 0..7
    const int bc = (t & 31) * 4;    // 0..124

    for (int k0 = 0; k0 < K; k0 += BKK) {
        float4 av = make_float4(0.f, 0.f, 0.f, 0.f);
        const int arow = row0 + ar;
        if (arow < M)
            av = *(const float4*)(A + (size_t)arow * K + k0 + ac);
        As[ac + 0][ar] = av.x; As[ac + 1][ar] = av.y;
        As[ac + 2][ar] = av.z; As[ac + 3][ar] = av.w;

        float4 bv = *(const float4*)(B + (size_t)(k0 + br) * Nc + col0 + bc);
        *(float4*)(&Bs[br][bc]) = bv;
        __syncthreads();

#pragma unroll
        for (int k = 0; k < BKK; ++k) {
            float a[8], b[8];
#pragma unroll
            for (int i = 0; i < 8; ++i) a[i] = As[k][ty * 8 + i];
#pragma unroll
            for (int j = 0; j < 8; ++j) b[j] = Bs[k][tx * 8 + j];
#pragma unroll
            for (int i = 0; i < 8; ++i)
#pragma unroll
                for (int j = 0; j < 8; ++j) acc[i][j] += a[i] * b[j];
        }
        __syncthreads();
    }

#pragma unroll
    for (int i = 0; i < 8; ++i) {
        const int r = row0 + ty * 8 + i;
        if (r < M) {
            float* cp = C + (size_t)r * Nc + col0 + tx * 8;
            float4 v0 = make_float4(acc[i][0], acc[i][1], acc[i][2], acc[i][3]);
            float4 v1 = make_float4(acc[i][4], acc[i][5], acc[i][6], acc[i][7]);
            *(float4*)cp = v0;
            *(float4*)(cp + 4) = v1;
        }
    }
}

// ------------- attention coefficients: es[n,h] = <h[n,h,:], a_src[h,:]> ------
__global__ __launch_bounds__(256) void attn_coef(
    const float* __restrict__ h, const float* __restrict__ asrc,
    const float* __restrict__ adst, float* __restrict__ es, float* __restrict__ ed)
{
    const int n = blockIdx.x;
    const int t = threadIdx.x;
    const float v = h[(size_t)n * NHD + t];
    float s1 = v * asrc[t];
    float s2 = v * adst[t];
#pragma unroll
    for (int off = 32; off; off >>= 1) {
        s1 += __shfl_down(s1, off, 64);
        s2 += __shfl_down(s2, off, 64);
    }
    if ((t & 63) == 0) {
        es[n * HEADS + (t >> 6)] = s1;
        ed[n * HEADS + (t >> 6)] = s2;
    }
}

// ------------- edge pass: ex = exp(leaky_relu(es[src]+ed[dst])), denom ------
__global__ void edge_attn(const int* __restrict__ ei,
                          const float* __restrict__ es, const float* __restrict__ ed,
                          float* __restrict__ ex, float* __restrict__ denom)
{
    const int e = blockIdx.x * 256 + threadIdx.x;
    if (e >= E_EDGES) return;
    const int s = ei[e];
    const int d = ei[E_EDGES + e];
    float4 a = *(const float4*)(es + s * 4);
    float4 b = *(const float4*)(ed + d * 4);
    float u0 = a.x + b.x, u1 = a.y + b.y, u2 = a.z + b.z, u3 = a.w + b.w;
    u0 = u0 > 0.f ? u0 : NEG_SLOPE * u0;
    u1 = u1 > 0.f ? u1 : NEG_SLOPE * u1;
    u2 = u2 > 0.f ? u2 : NEG_SLOPE * u2;
    u3 = u3 > 0.f ? u3 : NEG_SLOPE * u3;
    float4 r = make_float4(expf(u0), expf(u1), expf(u2), expf(u3));
    *(float4*)(ex + (size_t)e * 4) = r;
    atomicAdd(denom + d * 4 + 0, r.x);
    atomicAdd(denom + d * 4 + 1, r.y);
    atomicAdd(denom + d * 4 + 2, r.z);
    atomicAdd(denom + d * 4 + 3, r.w);
}

// ------------------------------ CSR build -----------------------------------
__global__ void hist_kernel(const int* __restrict__ ei, int* __restrict__ counts)
{
    const int e = blockIdx.x * 256 + threadIdx.x;
    if (e >= E_EDGES) return;
    atomicAdd(&counts[ei[E_EDGES + e]], 1);
}

__global__ __launch_bounds__(1024) void scan_kernel(const int* __restrict__ counts,
                                                    int* __restrict__ offsets)
{
    __shared__ int tmp[1024];
    __shared__ int carry;
    if (threadIdx.x == 0) { carry = 0; offsets[0] = 0; }
    __syncthreads();
    for (int base = 0; base < N_NODES; base += 1024) {
        const int i = base + threadIdx.x;
        int v = (i < N_NODES) ? counts[i] : 0;
        tmp[threadIdx.x] = v;
        __syncthreads();
        for (int off = 1; off < 1024; off <<= 1) {
            int t2 = (threadIdx.x >= off) ? tmp[threadIdx.x - off] : 0;
            __syncthreads();
            tmp[threadIdx.x] += t2;
            __syncthreads();
        }
        const int incl = tmp[threadIdx.x] + carry;
        if (i < N_NODES) offsets[i + 1] = incl;
        __syncthreads();
        if (threadIdx.x == 1023) carry = incl;
        __syncthreads();
    }
}

__global__ void copy_int_kernel(const int* __restrict__ src, int* __restrict__ dst, int n)
{
    const int i = blockIdx.x * 256 + threadIdx.x;
    if (i < n) dst[i] = src[i];
}

__global__ void scatter_kernel(const int* __restrict__ ei, int* __restrict__ cursor,
                               int* __restrict__ csr)
{
    const int e = blockIdx.x * 256 + threadIdx.x;
    if (e >= E_EDGES) return;
    const int d = ei[E_EDGES + e];
    const int pos = atomicAdd(&cursor[d], 1);
    csr[pos] = e;
}

// ----------------- aggregation: one wave per dst node -----------------------
__global__ __launch_bounds__(256) void aggregate_kernel(
    const float* __restrict__ h, const int* __restrict__ ei,
    const int* __restrict__ csr, const int* __restrict__ offsets,
    const float* __restrict__ ex, const float* __restrict__ denom,
    const float* __restrict__ bias, float* __restrict__ out)
{
    const int wid  = threadIdx.x >> 6;
    const int lane = threadIdx.x & 63;
    const int node = blockIdx.x * 4 + wid;
    if (node >= N_NODES) return;
    const int head = lane >> 4;          // col = lane*4 -> head = col/64
    const int col  = lane * 4;
    const float inv = 1.0f / (denom[node * 4 + head] + 1e-16f);
    const int beg = offsets[node], end = offsets[node + 1];
    float4 acc = make_float4(0.f, 0.f, 0.f, 0.f);
    for (int p = beg; p < end; ++p) {
        const int eid = csr[p];
        const int s = ei[eid];
        const float alpha = ex[(size_t)eid * 4 + head] * inv;
        float4 v = *(const float4*)(h + (size_t)s * NHD + col);
        acc.x += alpha * v.x;
        acc.y += alpha * v.y;
        acc.z += alpha * v.z;
        acc.w += alpha * v.w;
    }
    float4 bb = *(const float4*)(bias + col);
    acc.x = fmaxf(acc.x + bb.x, 0.f);
    acc.y = fmaxf(acc.y + bb.y, 0.f);
    acc.z = fmaxf(acc.z + bb.z, 0.f);
    acc.w = fmaxf(acc.w + bb.w, 0.f);
    *(float4*)(out + (size_t)node * NHD + col) = acc;
}

// ------------------------------ pooling -------------------------------------
__global__ void graph_offsets_kernel(const int* __restrict__ batch, int* __restrict__ goff)
{
    const int n = blockIdx.x * 256 + threadIdx.x;
    if (n >= N_NODES) return;
    const int b  = batch[n];
    const int bp = (n == 0) ? -1 : batch[n - 1];
    for (int g = bp + 1; g <= b; ++g) goff[g] = n;
    if (n == N_NODES - 1) {
        for (int g = b + 1; g <= NGRAPH; ++g) goff[g] = N_NODES;
    }
}

__global__ __launch_bounds__(128) void pool_kernel(
    const float* __restrict__ x, const float* __restrict__ h1,
    const float* __restrict__ h2, const int* __restrict__ goff,
    float* __restrict__ pooled)
{
    const int g = blockIdx.x;
    const int c = blockIdx.y * 128 + threadIdx.x;   // 0..639
    const int s = goff[g], e = goff[g + 1];
    float sum = 0.f;
    if (c < 128) {
        for (int r = s; r < e; ++r) sum += x[(size_t)r * INCH + c];
    } else if (c < 384) {
        const int cc = c - 128;
        for (int r = s; r < e; ++r) sum += h1[(size_t)r * NHD + cc];
    } else {
        const int cc = c - 384;
        for (int r = s; r < e; ++r) sum += h2[(size_t)r * NHD + cc];
    }
    const float cnt = (float)(e - s);
    pooled[(size_t)g * DCAT + c] = sum / fmaxf(cnt, 1.0f);
}

// ------------------------------ MLP head ------------------------------------
__global__ __launch_bounds__(256) void mlp_kernel(
    const float* __restrict__ pooled, const float* __restrict__ W3,
    const float* __restrict__ b3, const float* __restrict__ W4,
    const float* __restrict__ b4, float* __restrict__ out)
{
    const int g = blockIdx.x;
    __shared__ float p[DCAT];
    __shared__ float hm[256];
    for (int i = threadIdx.x; i < DCAT; i += 256) p[i] = pooled[(size_t)g * DCAT + i];
    __syncthreads();
    float s = b3[threadIdx.x];
    for (int k = 0; k < DCAT; ++k) s += p[k] * W3[(size_t)k * 256 + threadIdx.x];
    hm[threadIdx.x] = fmaxf(s, 0.f);
    __syncthreads();
    if (threadIdx.x < 128) {
        float o = b4[threadIdx.x];
        for (int k = 0; k < 256; ++k) o += hm[k] * W4[(size_t)k * 128 + threadIdx.x];
        out[(size_t)g * 128 + threadIdx.x] = o;
    }
}

// ------------------------------ launch --------------------------------------
extern "C" void kernel_launch(void* const* d_in, const int* in_sizes, int n_in,
                              void* d_out, int out_size, void* d_ws, size_t ws_size,
                              hipStream_t stream)
{
    const float* x     = (const float*)d_in[0];
    const int*   ei    = (const int*)d_in[1];
    const int*   batch = (const int*)d_in[2];
    const float* W1    = (const float*)d_in[3];
    const float* a1s   = (const float*)d_in[4];
    const float* a1d   = (const float*)d_in[5];
    const float* b1    = (const float*)d_in[6];
    const float* W2    = (const float*)d_in[7];
    const float* a2s   = (const float*)d_in[8];
    const float* a2d   = (const float*)d_in[9];
    const float* b2    = (const float*)d_in[10];
    const float* W3    = (const float*)d_in[11];
    const float* b3    = (const float*)d_in[12];
    const float* W4    = (const float*)d_in[13];
    const float* b4    = (const float*)d_in[14];
    float* out = (float*)d_out;

    // workspace carve
    size_t off = 0;
    auto carve = [&](size_t bytes) -> void* {
        void* p = (char*)d_ws + off;
        off = (off + bytes + 255) & ~(size_t)255;
        return p;
    };
    float* hraw   = (float*)carve((size_t)N_NODES * NHD * 4);
    float* h1     = (float*)carve((size_t)N_NODES * NHD * 4);
    float* h2     = (float*)carve((size_t)N_NODES * NHD * 4);
    float* ex     = (float*)carve((size_t)E_EDGES * HEADS * 4);
    float* denom  = (float*)carve((size_t)N_NODES * HEADS * 4);
    float* es     = (float*)carve((size_t)N_NODES * HEADS * 4);
    float* ed     = (float*)carve((size_t)N_NODES * HEADS * 4);
    float* pooled = (float*)carve((size_t)NGRAPH * DCAT * 4);
    int*   counts  = (int*)carve((size_t)N_NODES * 4);
    int*   offsets = (int*)carve((size_t)(N_NODES + 1) * 4);
    int*   cursor  = (int*)carve((size_t)N_NODES * 4);
    int*   csr     = (int*)carve((size_t)E_EDGES * 4);
    int*   goff    = (int*)carve((size_t)(NGRAPH + 1) * 4);

    const int egrid = (E_EDGES + 255) / 256;
    const int ngrid = (N_NODES + 255) / 256;

    // ---- CSR build (shared by both layers) ----
    hipMemsetAsync(counts, 0, (size_t)N_NODES * 4, stream);
    hist_kernel<<<egrid, 256, 0, stream>>>(ei, counts);
    scan_kernel<<<1, 1024, 0, stream>>>(counts, offsets);
    copy_int_kernel<<<ngrid, 256, 0, stream>>>(offsets, cursor, N_NODES);
    scatter_kernel<<<egrid, 256, 0, stream>>>(ei, cursor, csr);
    graph_offsets_kernel<<<ngrid, 256, 0, stream>>>(batch, goff);

    dim3 ggrid((N_NODES + BM - 1) / BM, NHD / BN);

    // ---- layer 1 ----
    gemm_f32<<<ggrid, 256, 0, stream>>>(x, W1, hraw, N_NODES, INCH, NHD);
    attn_coef<<<N_NODES, 256, 0, stream>>>(hraw, a1s, a1d, es, ed);
    hipMemsetAsync(denom, 0, (size_t)N_NODES * HEADS * 4, stream);
    edge_attn<<<egrid, 256, 0, stream>>>(ei, es, ed, ex, denom);
    aggregate_kernel<<<(N_NODES + 3) / 4, 256, 0, stream>>>(hraw, ei, csr, offsets,
                                                            ex, denom, b1, h1);
    // ---- layer 2 ----
    gemm_f32<<<ggrid, 256, 0, stream>>>(h1, W2, hraw, N_NODES, NHD, NHD);
    attn_coef<<<N_NODES, 256, 0, stream>>>(hraw, a2s, a2d, es, ed);
    hipMemsetAsync(denom, 0, (size_t)N_NODES * HEADS * 4, stream);
    edge_attn<<<egrid, 256, 0, stream>>>(ei, es, ed, ex, denom);
    aggregate_kernel<<<(N_NODES + 3) / 4, 256, 0, stream>>>(hraw, ei, csr, offsets,
                                                            ex, denom, b2, h2);

    // ---- pooling + MLP ----
    dim3 pgrid(NGRAPH, DCAT / 128);
    pool_kernel<<<pgrid, 128, 0, stream>>>(x, h1, h2, goff, pooled);
    mlp_kernel<<<NGRAPH, 256, 0, stream>>>(pooled, W3, b3, W4, b4, out);
}

// Round 2
// 1209.269 us; speedup vs baseline: 1.1556x; 1.1556x over previous
//
#include <hip/hip_runtime.h>
#include <cstdint>
#include <cstddef>

#define N_NODES 50000
#define E_EDGES 800000
#define INCH 128
#define HID 64
#define HEADS 4
#define NHD 256      // HEADS*HID
#define NGRAPH 64
#define DCAT 640     // 128 + 256 + 256
#define NEG_SLOPE 0.2f

// ---------------- GEMM: C[M,Nc] = A[M,K] @ B[K,Nc], fp32, row-major ----------
#define BM 128
#define BN 128
#define BKK 8

__global__ __launch_bounds__(256, 2) void gemm_f32(
    const float* __restrict__ A, const float* __restrict__ B,
    float* __restrict__ C, int M, int K, int Nc)
{
    __shared__ float As[BKK][BM];
    __shared__ float Bs[BKK][BN];
    const int t  = threadIdx.x;
    const int tx = t & 15, ty = t >> 4;
    const int row0 = blockIdx.x * BM;
    const int col0 = blockIdx.y * BN;

    float acc[8][8];
#pragma unroll
    for (int i = 0; i < 8; ++i)
#pragma unroll
        for (int j = 0; j < 8; ++j) acc[i][j] = 0.f;

    const int ar = t >> 1;          // 0..127
    const int ac = (t & 1) * 4;     // 0 or 4
    const int br = t >> 5;          // 0..7
    const int bc = (t & 31) * 4;    // 0..124

    for (int k0 = 0; k0 < K; k0 += BKK) {
        float4 av = make_float4(0.f, 0.f, 0.f, 0.f);
        const int arow = row0 + ar;
        if (arow < M)
            av = *(const float4*)(A + (size_t)arow * K + k0 + ac);
        As[ac + 0][ar] = av.x; As[ac + 1][ar] = av.y;
        As[ac + 2][ar] = av.z; As[ac + 3][ar] = av.w;

        float4 bv = *(const float4*)(B + (size_t)(k0 + br) * Nc + col0 + bc);
        *(float4*)(&Bs[br][bc]) = bv;
        __syncthreads();

#pragma unroll
        for (int k = 0; k < BKK; ++k) {
            float a[8], b[8];
#pragma unroll
            for (int i = 0; i < 8; ++i) a[i] = As[k][ty * 8 + i];
#pragma unroll
            for (int j = 0; j < 8; ++j) b[j] = Bs[k][tx * 8 + j];
#pragma unroll
            for (int i = 0; i < 8; ++i)
#pragma unroll
                for (int j = 0; j < 8; ++j) acc[i][j] += a[i] * b[j];
        }
        __syncthreads();
    }

#pragma unroll
    for (int i = 0; i < 8; ++i) {
        const int r = row0 + ty * 8 + i;
        if (r < M) {
            float* cp = C + (size_t)r * Nc + col0 + tx * 8;
            float4 v0 = make_float4(acc[i][0], acc[i][1], acc[i][2], acc[i][3]);
            float4 v1 = make_float4(acc[i][4], acc[i][5], acc[i][6], acc[i][7]);
            *(float4*)cp = v0;
            *(float4*)(cp + 4) = v1;
        }
    }
}

// ------------- attention coefficients: es[n,h] = <h[n,h,:], a_src[h,:]> ------
__global__ __launch_bounds__(256) void attn_coef(
    const float* __restrict__ h, const float* __restrict__ asrc,
    const float* __restrict__ adst, float* __restrict__ es, float* __restrict__ ed)
{
    const int n = blockIdx.x;
    const int t = threadIdx.x;
    const float v = h[(size_t)n * NHD + t];
    float s1 = v * asrc[t];
    float s2 = v * adst[t];
#pragma unroll
    for (int off = 32; off; off >>= 1) {
        s1 += __shfl_down(s1, off, 64);
        s2 += __shfl_down(s2, off, 64);
    }
    if ((t & 63) == 0) {
        es[n * HEADS + (t >> 6)] = s1;
        ed[n * HEADS + (t >> 6)] = s2;
    }
}

// ------------- edge pass: ex = exp(leaky_relu(es[src]+ed[dst])), denom ------
__global__ void edge_attn(const int* __restrict__ ei,
                          const float* __restrict__ es, const float* __restrict__ ed,
                          float* __restrict__ ex, float* __restrict__ denom)
{
    const int e = blockIdx.x * 256 + threadIdx.x;
    if (e >= E_EDGES) return;
    const int s = ei[e];
    const int d = ei[E_EDGES + e];
    float4 a = *(const float4*)(es + s * 4);
    float4 b = *(const float4*)(ed + d * 4);
    float u0 = a.x + b.x, u1 = a.y + b.y, u2 = a.z + b.z, u3 = a.w + b.w;
    u0 = u0 > 0.f ? u0 : NEG_SLOPE * u0;
    u1 = u1 > 0.f ? u1 : NEG_SLOPE * u1;
    u2 = u2 > 0.f ? u2 : NEG_SLOPE * u2;
    u3 = u3 > 0.f ? u3 : NEG_SLOPE * u3;
    float4 r = make_float4(expf(u0), expf(u1), expf(u2), expf(u3));
    *(float4*)(ex + (size_t)e * 4) = r;
    atomicAdd(denom + d * 4 + 0, r.x);
    atomicAdd(denom + d * 4 + 1, r.y);
    atomicAdd(denom + d * 4 + 2, r.z);
    atomicAdd(denom + d * 4 + 3, r.w);
}

// ------------------------------ CSR build -----------------------------------
__global__ void hist_kernel(const int* __restrict__ ei, int* __restrict__ counts)
{
    const int e = blockIdx.x * 256 + threadIdx.x;
    if (e >= E_EDGES) return;
    atomicAdd(&counts[ei[E_EDGES + e]], 1);
}

__global__ __launch_bounds__(1024) void scan_kernel(const int* __restrict__ counts,
                                                    int* __restrict__ offsets)
{
    __shared__ int tmp[1024];
    __shared__ int carry;
    if (threadIdx.x == 0) { carry = 0; offsets[0] = 0; }
    __syncthreads();
    for (int base = 0; base < N_NODES; base += 1024) {
        const int i = base + threadIdx.x;
        int v = (i < N_NODES) ? counts[i] : 0;
        tmp[threadIdx.x] = v;
        __syncthreads();
        for (int off = 1; off < 1024; off <<= 1) {
            int t2 = (threadIdx.x >= off) ? tmp[threadIdx.x - off] : 0;
            __syncthreads();
            tmp[threadIdx.x] += t2;
            __syncthreads();
        }
        const int incl = tmp[threadIdx.x] + carry;
        if (i < N_NODES) offsets[i + 1] = incl;
        __syncthreads();
        if (threadIdx.x == 1023) carry = incl;
        __syncthreads();
    }
}

__global__ void copy_int_kernel(const int* __restrict__ src, int* __restrict__ dst, int n)
{
    const int i = blockIdx.x * 256 + threadIdx.x;
    if (i < n) dst[i] = src[i];
}

__global__ void scatter_kernel(const int* __restrict__ ei, int* __restrict__ cursor,
                               int* __restrict__ csr)
{
    const int e = blockIdx.x * 256 + threadIdx.x;
    if (e >= E_EDGES) return;
    const int d = ei[E_EDGES + e];
    const int pos = atomicAdd(&cursor[d], 1);
    csr[pos] = e;
}

// ----------------- aggregation: one wave per dst node -----------------------
__global__ __launch_bounds__(256) void aggregate_kernel(
    const float* __restrict__ h, const int* __restrict__ ei,
    const int* __restrict__ csr, const int* __restrict__ offsets,
    const float* __restrict__ ex, const float* __restrict__ denom,
    const float* __restrict__ bias, float* __restrict__ out)
{
    const int wid  = threadIdx.x >> 6;
    const int lane = threadIdx.x & 63;
    const int node = blockIdx.x * 4 + wid;
    if (node >= N_NODES) return;
    const int head = lane >> 4;          // col = lane*4 -> head = col/64
    const int col  = lane * 4;
    const float inv = 1.0f / (denom[node * 4 + head] + 1e-16f);
    const int beg = offsets[node], end = offsets[node + 1];
    float4 acc = make_float4(0.f, 0.f, 0.f, 0.f);
    for (int p = beg; p < end; ++p) {
        const int eid = csr[p];
        const int s = ei[eid];
        const float alpha = ex[(size_t)eid * 4 + head] * inv;
        float4 v = *(const float4*)(h + (size_t)s * NHD + col);
        acc.x += alpha * v.x;
        acc.y += alpha * v.y;
        acc.z += alpha * v.z;
        acc.w += alpha * v.w;
    }
    float4 bb = *(const float4*)(bias + col);
    acc.x = fmaxf(acc.x + bb.x, 0.f);
    acc.y = fmaxf(acc.y + bb.y, 0.f);
    acc.z = fmaxf(acc.z + bb.z, 0.f);
    acc.w = fmaxf(acc.w + bb.w, 0.f);
    *(float4*)(out + (size_t)node * NHD + col) = acc;
}

// ------------------------------ pooling -------------------------------------
__global__ void graph_offsets_kernel(const int* __restrict__ batch, int* __restrict__ goff)
{
    const int n = blockIdx.x * 256 + threadIdx.x;
    if (n >= N_NODES) return;
    const int b  = batch[n];
    const int bp = (n == 0) ? -1 : batch[n - 1];
    for (int g = bp + 1; g <= b; ++g) goff[g] = n;
    if (n == N_NODES - 1) {
        for (int g = b + 1; g <= NGRAPH; ++g) goff[g] = N_NODES;
    }
}

// pool v2: 640 threads = one per concat column; each block sums a chunk of
// PRB rows, batching per-graph segments (batch is sorted) and flushing one
// atomicAdd per segment per thread into sums[G,DCAT].
#define PRB 128

__global__ __launch_bounds__(640) void pool_sum_kernel(
    const float* __restrict__ x, const float* __restrict__ h1,
    const float* __restrict__ h2, const int* __restrict__ batch,
    float* __restrict__ sums)
{
    __shared__ int bsh[PRB];
    const int c  = threadIdx.x;            // 0..639
    const int r0 = blockIdx.x * PRB;
    const int r1 = min(N_NODES, r0 + PRB);
    const int nr = r1 - r0;
    if (c < nr) bsh[c] = batch[r0 + c];
    __syncthreads();

    const float* src; int ld, cc;
    if (c < INCH)            { src = x;  ld = INCH; cc = c; }
    else if (c < INCH + NHD) { src = h1; ld = NHD;  cc = c - INCH; }
    else                     { src = h2; ld = NHD;  cc = c - INCH - NHD; }

    float sum = 0.f;
    int g = bsh[0];
    for (int i = 0; i < nr; ++i) {
        const int gb = bsh[i];
        if (gb != g) {
            atomicAdd(&sums[g * DCAT + c], sum);
            sum = 0.f;
            g = gb;
        }
        sum += src[(size_t)(r0 + i) * ld + cc];
    }
    atomicAdd(&sums[g * DCAT + c], sum);
}

__global__ void pool_finalize_kernel(const float* __restrict__ sums,
                                     const int* __restrict__ goff,
                                     float* __restrict__ pooled)
{
    const int i = blockIdx.x * 256 + threadIdx.x;
    if (i >= NGRAPH * DCAT) return;
    const int g = i / DCAT;
    const float cnt = (float)(goff[g + 1] - goff[g]);
    pooled[i] = sums[i] / fmaxf(cnt, 1.0f);
}

// ------------------------------ MLP head ------------------------------------
__global__ __launch_bounds__(256) void mlp_kernel(
    const float* __restrict__ pooled, const float* __restrict__ W3,
    const float* __restrict__ b3, const float* __restrict__ W4,
    const float* __restrict__ b4, float* __restrict__ out)
{
    const int g = blockIdx.x;
    __shared__ float p[DCAT];
    __shared__ float hm[256];
    for (int i = threadIdx.x; i < DCAT; i += 256) p[i] = pooled[(size_t)g * DCAT + i];
    __syncthreads();
    float s = b3[threadIdx.x];
    for (int k = 0; k < DCAT; ++k) s += p[k] * W3[(size_t)k * 256 + threadIdx.x];
    hm[threadIdx.x] = fmaxf(s, 0.f);
    __syncthreads();
    if (threadIdx.x < 128) {
        float o = b4[threadIdx.x];
        for (int k = 0; k < 256; ++k) o += hm[k] * W4[(size_t)k * 128 + threadIdx.x];
        out[(size_t)g * 128 + threadIdx.x] = o;
    }
}

// ------------------------------ launch --------------------------------------
extern "C" void kernel_launch(void* const* d_in, const int* in_sizes, int n_in,
                              void* d_out, int out_size, void* d_ws, size_t ws_size,
                              hipStream_t stream)
{
    const float* x     = (const float*)d_in[0];
    const int*   ei    = (const int*)d_in[1];
    const int*   batch = (const int*)d_in[2];
    const float* W1    = (const float*)d_in[3];
    const float* a1s   = (const float*)d_in[4];
    const float* a1d   = (const float*)d_in[5];
    const float* b1    = (const float*)d_in[6];
    const float* W2    = (const float*)d_in[7];
    const float* a2s   = (const float*)d_in[8];
    const float* a2d   = (const float*)d_in[9];
    const float* b2    = (const float*)d_in[10];
    const float* W3    = (const float*)d_in[11];
    const float* b3    = (const float*)d_in[12];
    const float* W4    = (const float*)d_in[13];
    const float* b4    = (const float*)d_in[14];
    float* out = (float*)d_out;

    // workspace carve
    size_t off = 0;
    auto carve = [&](size_t bytes) -> void* {
        void* p = (char*)d_ws + off;
        off = (off + bytes + 255) & ~(size_t)255;
        return p;
    };
    float* hraw   = (float*)carve((size_t)N_NODES * NHD * 4);
    float* h1     = (float*)carve((size_t)N_NODES * NHD * 4);
    float* h2     = (float*)carve((size_t)N_NODES * NHD * 4);
    float* ex     = (float*)carve((size_t)E_EDGES * HEADS * 4);
    float* denom  = (float*)carve((size_t)N_NODES * HEADS * 4);
    float* es     = (float*)carve((size_t)N_NODES * HEADS * 4);
    float* ed     = (float*)carve((size_t)N_NODES * HEADS * 4);
    float* pooled = (float*)carve((size_t)NGRAPH * DCAT * 4);
    float* psums  = (float*)carve((size_t)NGRAPH * DCAT * 4);
    int*   counts  = (int*)carve((size_t)N_NODES * 4);
    int*   offsets = (int*)carve((size_t)(N_NODES + 1) * 4);
    int*   cursor  = (int*)carve((size_t)N_NODES * 4);
    int*   csr     = (int*)carve((size_t)E_EDGES * 4);
    int*   goff    = (int*)carve((size_t)(NGRAPH + 1) * 4);

    const int egrid = (E_EDGES + 255) / 256;
    const int ngrid = (N_NODES + 255) / 256;

    // ---- CSR build (shared by both layers) ----
    hipMemsetAsync(counts, 0, (size_t)N_NODES * 4, stream);
    hist_kernel<<<egrid, 256, 0, stream>>>(ei, counts);
    scan_kernel<<<1, 1024, 0, stream>>>(counts, offsets);
    copy_int_kernel<<<ngrid, 256, 0, stream>>>(offsets, cursor, N_NODES);
    scatter_kernel<<<egrid, 256, 0, stream>>>(ei, cursor, csr);
    graph_offsets_kernel<<<ngrid, 256, 0, stream>>>(batch, goff);

    dim3 ggrid((N_NODES + BM - 1) / BM, NHD / BN);

    // ---- layer 1 ----
    gemm_f32<<<ggrid, 256, 0, stream>>>(x, W1, hraw, N_NODES, INCH, NHD);
    attn_coef<<<N_NODES, 256, 0, stream>>>(hraw, a1s, a1d, es, ed);
    hipMemsetAsync(denom, 0, (size_t)N_NODES * HEADS * 4, stream);
    edge_attn<<<egrid, 256, 0, stream>>>(ei, es, ed, ex, denom);
    aggregate_kernel<<<(N_NODES + 3) / 4, 256, 0, stream>>>(hraw, ei, csr, offsets,
                                                            ex, denom, b1, h1);
    // ---- layer 2 ----
    gemm_f32<<<ggrid, 256, 0, stream>>>(h1, W2, hraw, N_NODES, NHD, NHD);
    attn_coef<<<N_NODES, 256, 0, stream>>>(hraw, a2s, a2d, es, ed);
    hipMemsetAsync(denom, 0, (size_t)N_NODES * HEADS * 4, stream);
    edge_attn<<<egrid, 256, 0, stream>>>(ei, es, ed, ex, denom);
    aggregate_kernel<<<(N_NODES + 3) / 4, 256, 0, stream>>>(hraw, ei, csr, offsets,
                                                            ex, denom, b2, h2);

    // ---- pooling + MLP ----
    hipMemsetAsync(psums, 0, (size_t)NGRAPH * DCAT * 4, stream);
    pool_sum_kernel<<<(N_NODES + PRB - 1) / PRB, 640, 0, stream>>>(x, h1, h2, batch, psums);
    pool_finalize_kernel<<<(NGRAPH * DCAT + 255) / 256, 256, 0, stream>>>(psums, goff, pooled);
    mlp_kernel<<<NGRAPH, 256, 0, stream>>>(pooled, W3, b3, W4, b4, out);
}

// Round 3
// 835.340 us; speedup vs baseline: 1.6729x; 1.4476x over previous
//
#include <hip/hip_runtime.h>
#include <cstdint>
#include <cstddef>

#define N_NODES 50000
#define E_EDGES 800000
#define INCH 128
#define HID 64
#define HEADS 4
#define NHD 256      // HEADS*HID
#define NGRAPH 64
#define DCAT 640     // 128 + 256 + 256
#define NEG_SLOPE 0.2f

// ---------------- GEMM: C[M,Nc] = A[M,K] @ B[K,Nc], fp32, row-major ----------
#define BM 128
#define BN 128
#define BKK 8

__global__ __launch_bounds__(256, 2) void gemm_f32(
    const float* __restrict__ A, const float* __restrict__ B,
    float* __restrict__ C, int M, int K, int Nc)
{
    __shared__ float As[BKK][BM];
    __shared__ float Bs[BKK][BN];
    const int t  = threadIdx.x;
    const int tx = t & 15, ty = t >> 4;
    const int row0 = blockIdx.x * BM;
    const int col0 = blockIdx.y * BN;

    float acc[8][8];
#pragma unroll
    for (int i = 0; i < 8; ++i)
#pragma unroll
        for (int j = 0; j < 8; ++j) acc[i][j] = 0.f;

    const int ar = t >> 1;          // 0..127
    const int ac = (t & 1) * 4;     // 0 or 4
    const int br = t >> 5;          // 0..7
    const int bc = (t & 31) * 4;    // 0..124

    for (int k0 = 0; k0 < K; k0 += BKK) {
        float4 av = make_float4(0.f, 0.f, 0.f, 0.f);
        const int arow = row0 + ar;
        if (arow < M)
            av = *(const float4*)(A + (size_t)arow * K + k0 + ac);
        As[ac + 0][ar] = av.x; As[ac + 1][ar] = av.y;
        As[ac + 2][ar] = av.z; As[ac + 3][ar] = av.w;

        float4 bv = *(const float4*)(B + (size_t)(k0 + br) * Nc + col0 + bc);
        *(float4*)(&Bs[br][bc]) = bv;
        __syncthreads();

#pragma unroll
        for (int k = 0; k < BKK; ++k) {
            float a[8], b[8];
#pragma unroll
            for (int i = 0; i < 8; ++i) a[i] = As[k][ty * 8 + i];
#pragma unroll
            for (int j = 0; j < 8; ++j) b[j] = Bs[k][tx * 8 + j];
#pragma unroll
            for (int i = 0; i < 8; ++i)
#pragma unroll
                for (int j = 0; j < 8; ++j) acc[i][j] += a[i] * b[j];
        }
        __syncthreads();
    }

#pragma unroll
    for (int i = 0; i < 8; ++i) {
        const int r = row0 + ty * 8 + i;
        if (r < M) {
            float* cp = C + (size_t)r * Nc + col0 + tx * 8;
            float4 v0 = make_float4(acc[i][0], acc[i][1], acc[i][2], acc[i][3]);
            float4 v1 = make_float4(acc[i][4], acc[i][5], acc[i][6], acc[i][7]);
            *(float4*)cp = v0;
            *(float4*)(cp + 4) = v1;
        }
    }
}

// ------------- attention coefficients: es[n,h] = <h[n,h,:], a_src[h,:]> ------
__global__ __launch_bounds__(256) void attn_coef(
    const float* __restrict__ h, const float* __restrict__ asrc,
    const float* __restrict__ adst, float* __restrict__ es, float* __restrict__ ed)
{
    const int n = blockIdx.x;
    const int t = threadIdx.x;
    const float v = h[(size_t)n * NHD + t];
    float s1 = v * asrc[t];
    float s2 = v * adst[t];
#pragma unroll
    for (int off = 32; off; off >>= 1) {
        s1 += __shfl_down(s1, off, 64);
        s2 += __shfl_down(s2, off, 64);
    }
    if ((t & 63) == 0) {
        es[n * HEADS + (t >> 6)] = s1;
        ed[n * HEADS + (t >> 6)] = s2;
    }
}

// ------------------------------ CSR build -----------------------------------
__global__ void hist_kernel(const int* __restrict__ ei, int* __restrict__ counts)
{
    const int e = blockIdx.x * 256 + threadIdx.x;
    if (e >= E_EDGES) return;
    atomicAdd(&counts[ei[E_EDGES + e]], 1);
}

__global__ __launch_bounds__(1024) void scan_kernel(const int* __restrict__ counts,
                                                    int* __restrict__ offsets)
{
    __shared__ int tmp[1024];
    __shared__ int carry;
    if (threadIdx.x == 0) { carry = 0; offsets[0] = 0; }
    __syncthreads();
    for (int base = 0; base < N_NODES; base += 1024) {
        const int i = base + threadIdx.x;
        int v = (i < N_NODES) ? counts[i] : 0;
        tmp[threadIdx.x] = v;
        __syncthreads();
        for (int off = 1; off < 1024; off <<= 1) {
            int t2 = (threadIdx.x >= off) ? tmp[threadIdx.x - off] : 0;
            __syncthreads();
            tmp[threadIdx.x] += t2;
            __syncthreads();
        }
        const int incl = tmp[threadIdx.x] + carry;
        if (i < N_NODES) offsets[i + 1] = incl;
        __syncthreads();
        if (threadIdx.x == 1023) carry = incl;
        __syncthreads();
    }
}

__global__ void copy_int_kernel(const int* __restrict__ src, int* __restrict__ dst, int n)
{
    const int i = blockIdx.x * 256 + threadIdx.x;
    if (i < n) dst[i] = src[i];
}

__global__ void scatter_kernel(const int* __restrict__ ei, int* __restrict__ cursor,
                               int* __restrict__ csr)
{
    const int e = blockIdx.x * 256 + threadIdx.x;
    if (e >= E_EDGES) return;
    const int d = ei[E_EDGES + e];
    const int pos = atomicAdd(&cursor[d], 1);
    csr[pos] = e;
}

// ------- fused softmax + aggregation: one wave per dst node ------------------
// Per 64-edge chunk: lane l preloads edge (csr -> src -> es[src]) and
// precomputes exp(leaky_relu(es+ed)) for all 4 heads in registers. Inner loop
// per edge is shfl broadcasts + one coalesced 1KB h-row gather + FMAs; the
// softmax denominator accumulates in-register (no atomics, no denom array).
__global__ __launch_bounds__(256) void aggregate_fused(
    const float* __restrict__ h, const int* __restrict__ ei,
    const int* __restrict__ csr, const int* __restrict__ offsets,
    const float* __restrict__ es, const float* __restrict__ ed,
    const float* __restrict__ bias, float* __restrict__ out)
{
    const int wid  = threadIdx.x >> 6;
    const int lane = threadIdx.x & 63;
    const int node = blockIdx.x * 4 + wid;
    if (node >= N_NODES) return;
    const int head = lane >> 4;          // col = lane*4 -> head = col/64
    const int col  = lane * 4;

    const float4 edv = *(const float4*)(ed + node * 4);   // all 4 heads
    const int beg = offsets[node], end = offsets[node + 1];

    float4 acc = make_float4(0.f, 0.f, 0.f, 0.f);
    float dsum = 0.f;

    for (int base = beg; base < end; base += 64) {
        const int m = min(64, end - base);
        int s_l = 0;
        float4 w4 = make_float4(0.f, 0.f, 0.f, 0.f);
        if (lane < m) {
            const int eid = csr[base + lane];
            s_l = ei[eid];
            float4 e4 = *(const float4*)(es + s_l * 4);
            float u0 = e4.x + edv.x, u1 = e4.y + edv.y;
            float u2 = e4.z + edv.z, u3 = e4.w + edv.w;
            u0 = u0 > 0.f ? u0 : NEG_SLOPE * u0;
            u1 = u1 > 0.f ? u1 : NEG_SLOPE * u1;
            u2 = u2 > 0.f ? u2 : NEG_SLOPE * u2;
            u3 = u3 > 0.f ? u3 : NEG_SLOPE * u3;
            w4 = make_float4(expf(u0), expf(u1), expf(u2), expf(u3));
        }
        for (int i = 0; i < m; ++i) {
            const int s  = __shfl(s_l, i, 64);
            const float wx = __shfl(w4.x, i, 64);
            const float wy = __shfl(w4.y, i, 64);
            const float wz = __shfl(w4.z, i, 64);
            const float ww = __shfl(w4.w, i, 64);
            const float w = head == 0 ? wx : head == 1 ? wy : head == 2 ? wz : ww;
            const float4 v = *(const float4*)(h + (size_t)s * NHD + col);
            acc.x += w * v.x;
            acc.y += w * v.y;
            acc.z += w * v.z;
            acc.w += w * v.w;
            dsum += w;
        }
    }

    const float inv = 1.0f / (dsum + 1e-16f);
    const float4 bb = *(const float4*)(bias + col);
    float4 o;
    o.x = fmaxf(acc.x * inv + bb.x, 0.f);
    o.y = fmaxf(acc.y * inv + bb.y, 0.f);
    o.z = fmaxf(acc.z * inv + bb.z, 0.f);
    o.w = fmaxf(acc.w * inv + bb.w, 0.f);
    *(float4*)(out + (size_t)node * NHD + col) = o;
}

// ------------------------------ pooling -------------------------------------
__global__ void graph_offsets_kernel(const int* __restrict__ batch, int* __restrict__ goff)
{
    const int n = blockIdx.x * 256 + threadIdx.x;
    if (n >= N_NODES) return;
    const int b  = batch[n];
    const int bp = (n == 0) ? -1 : batch[n - 1];
    for (int g = bp + 1; g <= b; ++g) goff[g] = n;
    if (n == N_NODES - 1) {
        for (int g = b + 1; g <= NGRAPH; ++g) goff[g] = N_NODES;
    }
}

#define PRB 128

__global__ __launch_bounds__(640) void pool_sum_kernel(
    const float* __restrict__ x, const float* __restrict__ h1,
    const float* __restrict__ h2, const int* __restrict__ batch,
    float* __restrict__ sums)
{
    __shared__ int bsh[PRB];
    const int c  = threadIdx.x;            // 0..639
    const int r0 = blockIdx.x * PRB;
    const int r1 = min(N_NODES, r0 + PRB);
    const int nr = r1 - r0;
    if (c < nr) bsh[c] = batch[r0 + c];
    __syncthreads();

    const float* src; int ld, cc;
    if (c < INCH)            { src = x;  ld = INCH; cc = c; }
    else if (c < INCH + NHD) { src = h1; ld = NHD;  cc = c - INCH; }
    else                     { src = h2; ld = NHD;  cc = c - INCH - NHD; }

    float sum = 0.f;
    int g = bsh[0];
    for (int i = 0; i < nr; ++i) {
        const int gb = bsh[i];
        if (gb != g) {
            atomicAdd(&sums[g * DCAT + c], sum);
            sum = 0.f;
            g = gb;
        }
        sum += src[(size_t)(r0 + i) * ld + cc];
    }
    atomicAdd(&sums[g * DCAT + c], sum);
}

__global__ void pool_finalize_kernel(const float* __restrict__ sums,
                                     const int* __restrict__ goff,
                                     float* __restrict__ pooled)
{
    const int i = blockIdx.x * 256 + threadIdx.x;
    if (i >= NGRAPH * DCAT) return;
    const int g = i / DCAT;
    const float cnt = (float)(goff[g + 1] - goff[g]);
    pooled[i] = sums[i] / fmaxf(cnt, 1.0f);
}

// ------------------------------ MLP head ------------------------------------
__global__ __launch_bounds__(256) void mlp_kernel(
    const float* __restrict__ pooled, const float* __restrict__ W3,
    const float* __restrict__ b3, const float* __restrict__ W4,
    const float* __restrict__ b4, float* __restrict__ out)
{
    const int g = blockIdx.x;
    __shared__ float p[DCAT];
    __shared__ float hm[256];
    for (int i = threadIdx.x; i < DCAT; i += 256) p[i] = pooled[(size_t)g * DCAT + i];
    __syncthreads();
    float s = b3[threadIdx.x];
    for (int k = 0; k < DCAT; ++k) s += p[k] * W3[(size_t)k * 256 + threadIdx.x];
    hm[threadIdx.x] = fmaxf(s, 0.f);
    __syncthreads();
    if (threadIdx.x < 128) {
        float o = b4[threadIdx.x];
        for (int k = 0; k < 256; ++k) o += hm[k] * W4[(size_t)k * 128 + threadIdx.x];
        out[(size_t)g * 128 + threadIdx.x] = o;
    }
}

// ------------------------------ launch --------------------------------------
extern "C" void kernel_launch(void* const* d_in, const int* in_sizes, int n_in,
                              void* d_out, int out_size, void* d_ws, size_t ws_size,
                              hipStream_t stream)
{
    const float* x     = (const float*)d_in[0];
    const int*   ei    = (const int*)d_in[1];
    const int*   batch = (const int*)d_in[2];
    const float* W1    = (const float*)d_in[3];
    const float* a1s   = (const float*)d_in[4];
    const float* a1d   = (const float*)d_in[5];
    const float* b1    = (const float*)d_in[6];
    const float* W2    = (const float*)d_in[7];
    const float* a2s   = (const float*)d_in[8];
    const float* a2d   = (const float*)d_in[9];
    const float* b2    = (const float*)d_in[10];
    const float* W3    = (const float*)d_in[11];
    const float* b3    = (const float*)d_in[12];
    const float* W4    = (const float*)d_in[13];
    const float* b4    = (const float*)d_in[14];
    float* out = (float*)d_out;

    // workspace carve
    size_t off = 0;
    auto carve = [&](size_t bytes) -> void* {
        void* p = (char*)d_ws + off;
        off = (off + bytes + 255) & ~(size_t)255;
        return p;
    };
    float* hraw   = (float*)carve((size_t)N_NODES * NHD * 4);
    float* h1     = (float*)carve((size_t)N_NODES * NHD * 4);
    float* h2     = (float*)carve((size_t)N_NODES * NHD * 4);
    float* es     = (float*)carve((size_t)N_NODES * HEADS * 4);
    float* ed     = (float*)carve((size_t)N_NODES * HEADS * 4);
    float* pooled = (float*)carve((size_t)NGRAPH * DCAT * 4);
    float* psums  = (float*)carve((size_t)NGRAPH * DCAT * 4);
    int*   counts  = (int*)carve((size_t)N_NODES * 4);
    int*   offsets = (int*)carve((size_t)(N_NODES + 1) * 4);
    int*   cursor  = (int*)carve((size_t)N_NODES * 4);
    int*   csr     = (int*)carve((size_t)E_EDGES * 4);
    int*   goff    = (int*)carve((size_t)(NGRAPH + 1) * 4);

    const int egrid = (E_EDGES + 255) / 256;
    const int ngrid = (N_NODES + 255) / 256;

    // ---- CSR build (shared by both layers) ----
    hipMemsetAsync(counts, 0, (size_t)N_NODES * 4, stream);
    hist_kernel<<<egrid, 256, 0, stream>>>(ei, counts);
    scan_kernel<<<1, 1024, 0, stream>>>(counts, offsets);
    copy_int_kernel<<<ngrid, 256, 0, stream>>>(offsets, cursor, N_NODES);
    scatter_kernel<<<egrid, 256, 0, stream>>>(ei, cursor, csr);
    graph_offsets_kernel<<<ngrid, 256, 0, stream>>>(batch, goff);

    dim3 ggrid((N_NODES + BM - 1) / BM, NHD / BN);

    // ---- layer 1 ----
    gemm_f32<<<ggrid, 256, 0, stream>>>(x, W1, hraw, N_NODES, INCH, NHD);
    attn_coef<<<N_NODES, 256, 0, stream>>>(hraw, a1s, a1d, es, ed);
    aggregate_fused<<<(N_NODES + 3) / 4, 256, 0, stream>>>(hraw, ei, csr, offsets,
                                                           es, ed, b1, h1);
    // ---- layer 2 ----
    gemm_f32<<<ggrid, 256, 0, stream>>>(h1, W2, hraw, N_NODES, NHD, NHD);
    attn_coef<<<N_NODES, 256, 0, stream>>>(hraw, a2s, a2d, es, ed);
    aggregate_fused<<<(N_NODES + 3) / 4, 256, 0, stream>>>(hraw, ei, csr, offsets,
                                                           es, ed, b2, h2);

    // ---- pooling + MLP ----
    hipMemsetAsync(psums, 0, (size_t)NGRAPH * DCAT * 4, stream);
    pool_sum_kernel<<<(N_NODES + PRB - 1) / PRB, 640, 0, stream>>>(x, h1, h2, batch, psums);
    pool_finalize_kernel<<<(NGRAPH * DCAT + 255) / 256, 256, 0, stream>>>(psums, goff, pooled);
    mlp_kernel<<<NGRAPH, 256, 0, stream>>>(pooled, W3, b3, W4, b4, out);
}